// Round 15
// baseline (722.089 us; speedup 1.0000x reference)
//
#include <hip/hip_runtime.h>
#include <hip/hip_cooperative_groups.h>

namespace cg = cooperative_groups;

#define N_NODES 50000
#define N_EDGES 800000
#define D 64
#define NBUCK 782            // ceil(50000/64) buckets of 64 dst nodes
#define BINBLK 256           // binning blocks
#define EPB 3125             // edges per bin block (256*3125 = 800000)
#define ECHUNK 13            // ceil(3125/256)
#define GEMMBLK 3125         // gemm tiles, 16 rows each
#define AGGBLK 12500         // aggregate virtual blocks, 4 nodes each
#define CAP 1536             // fixed bucket capacity (mean 1024 + 16 sigma)
#define FIXSCALE 4194304.0f  // 2^22 fixed-point for weighted degree
#define GRID 768             // cooperative grid (3 blocks/CU; capacity 4/CU)

// ---------------- helpers ----------------

__device__ inline unsigned short f2bf(float f) {
    unsigned u = __float_as_uint(f);
    unsigned r = (u + 0x7FFFu + ((u >> 16) & 1u)) >> 16;   // RNE
    return (unsigned short)r;
}
__device__ inline float bf2f(unsigned short h) {
    return __uint_as_float(((unsigned)h) << 16);
}
__device__ inline int wave_incl_scan(int v, int lane) {
#pragma unroll
    for (int off = 1; off < 64; off <<= 1) {
        int n = __shfl_up(v, off, 64);
        if (lane >= off) v += n;
    }
    return v;
}

// LDS union shared by all phases (max 17.4 KB -> 9 blocks/CU by LDS)
union ShU {
    int lh[NBUCK];                                                    // bin
    struct { float Ws[D][D]; float Xs[4][D]; } gm;                    // gemm
    struct { unsigned long long stage[CAP];
             unsigned long long cw[64]; int off2[64]; } so;           // sort
};

// ---------------- fused cooperative kernel ----------------

__global__ __launch_bounds__(256, 4) void k_fused(
        const int* __restrict__ src, const int* __restrict__ dst,
        const float* __restrict__ ew, int* __restrict__ gcur,
        unsigned long long* __restrict__ binned,
        const float* __restrict__ x, const float* __restrict__ W,
        unsigned short* __restrict__ hb,
        unsigned* __restrict__ csr, unsigned* __restrict__ rc,
        float* __restrict__ dinv, const float* __restrict__ bias,
        float* __restrict__ out) {
    cg::grid_group grid = cg::this_grid();
    __shared__ ShU sh;
    int t = threadIdx.x;
    int bid = blockIdx.x;

    int rd[ECHUNK]; int rs[ECHUNK]; float rw[ECHUNK];   // register-staged edges

    // ---------- P0: zero gcur + bin pass1 (count)  ||  gemm ----------
    if (bid < BINBLK) {
        int zi = bid * 256 + t;
        if (zi < NBUCK) gcur[zi] = 0;     // blocks 0..3 cover all buckets
        int* lh = sh.lh;
        for (int i = t; i < NBUCK; i += 256) lh[i] = 0;
        __syncthreads();
        int base = bid * EPB;
#pragma unroll
        for (int i = 0; i < ECHUNK; ++i) {
            int k = i * 256 + t;
            rd[i] = -1;
            if (k < EPB) {
                int e = base + k;
                rd[i] = dst[e];
                rs[i] = src[e];
                rw[i] = ew[e];
                atomicAdd(&lh[rd[i] >> 6], 1);
            }
        }
        __syncthreads();
    } else {
        float (*Ws)[D] = sh.gm.Ws;
        float (*Xs)[D] = sh.gm.Xs;
        for (int k = t; k < D * D; k += 256) Ws[k / D][k % D] = W[k];
        int r = t >> 6, c = t & 63;
        for (int vb = bid - BINBLK; vb < GEMMBLK; vb += GRID - BINBLK) {
            int base = vb * 16;
            for (int g = 0; g < 4; ++g) {
                int row = base + g * 4 + r;
                __syncthreads();   // covers Ws staging (first) and Xs reuse
                Xs[r][c] = (row < N_NODES) ? x[(size_t)row * D + c] : 0.0f;
                __syncthreads();
                float acc = 0.0f;
#pragma unroll
                for (int k = 0; k < D; ++k) acc = fmaf(Xs[r][k], Ws[k][c], acc);
                if (row < N_NODES) hb[(size_t)row * D + c] = f2bf(acc);
            }
        }
    }
    __threadfence();
    grid.sync();
    __threadfence();

    // ---------- P1: bin blocks reserve + scatter from registers ----------
    if (bid < BINBLK) {
        int* lh = sh.lh;
        for (int i = t; i < NBUCK; i += 256) {
            int c = lh[i];
            lh[i] = (c > 0) ? atomicAdd(&gcur[i], c) : 0;   // block's run base
        }
        __syncthreads();
#pragma unroll
        for (int i = 0; i < ECHUNK; ++i) {
            if (rd[i] >= 0) {
                int bkt = rd[i] >> 6;
                int pos = atomicAdd(&lh[bkt], 1);
                if (pos < CAP)
                    binned[(size_t)bkt * CAP + pos] =
                        ((unsigned long long)__float_as_uint(rw[i]) << 32)
                      | ((unsigned)rs[i] << 16) | (unsigned)rd[i];
            }
        }
    }
    __threadfence();
    grid.sync();
    __threadfence();

    // ---------- P2: sortbucket (grid-strided) ----------
    for (int b = bid; b < NBUCK; b += GRID) {
        unsigned long long* stage = sh.so.stage;
        unsigned long long* cw = sh.so.cw;
        int* off2 = sh.so.off2;
        __syncthreads();               // protect LDS reuse across iterations
        if (t < 64) cw[t] = 0ULL;
        __syncthreads();
        size_t beg = (size_t)b * CAP;
        int len = min(gcur[b], CAP);
        for (int k = t; k < len; k += 256) {
            unsigned long long p = binned[beg + k];
            stage[k] = p;
            int dl = (int)(p & 63);
            float w = __uint_as_float((unsigned)(p >> 32));
            atomicAdd(&cw[dl],
                      (1ULL << 40) | (unsigned long long)__float2uint_rn(w * FIXSCALE));
        }
        __syncthreads();
        if (t < 64) {
            int c = (int)(cw[t] >> 40);
            float wfix = (float)(cw[t] & ((1ULL << 40) - 1ULL));
            int inc = wave_incl_scan(c, t);
            int excl = inc - c;
            off2[t] = excl;
            int node = b * 64 + t;
            if (node < N_NODES) {
                rc[node] = ((unsigned)c << 12) | (unsigned)excl;
                dinv[node] = rsqrtf(1.0f + wfix * (1.0f / FIXSCALE));
            }
        }
        __syncthreads();
        for (int k = t; k < len; k += 256) {
            unsigned long long p = stage[k];
            int dl = (int)(p & 63);
            int r = atomicAdd(&off2[dl], 1);
            unsigned short ewb = f2bf(__uint_as_float((unsigned)(p >> 32)));
            csr[beg + r] = ((unsigned)ewb << 16) | (unsigned)((p >> 16) & 0xffffu);
        }
    }
    __threadfence();
    grid.sync();
    __threadfence();

    // ---------- P3: aggregate (grid-strided, uniform half-split) ----------
    int lane = t & 63;
    int half = lane >> 5;
    int cl = lane & 31;              // column pair: cols 2cl, 2cl+1
    for (int vb = bid; vb < AGGBLK; vb += GRID) {
        int node = vb * 4 + (t >> 6);   // vb<12500 -> node<50000 always valid
        float di = dinv[node];
        unsigned r = rc[node];
        int cnt = (int)(r >> 12);
        size_t beg = (size_t)(node >> 6) * CAP + (r & 0xFFFu);
        float a0, a1, p0 = 0.0f, p1 = 0.0f;
        {   // self-loop term, counted once (half 0 lanes)
            unsigned hd = *(const unsigned*)(hb + (size_t)node * D + 2 * cl);
            float m = (half == 0) ? di : 0.0f;
            a0 = m * bf2f((unsigned short)hd);
            a1 = m * bf2f((unsigned short)(hd >> 16));
        }
        for (int b0 = 0; b0 < cnt; b0 += 64) {
            int n = min(64, cnt - b0);
            int my_src = 0;
            float my_ew = 0.0f;
            if (lane < n) {
                unsigned q = csr[beg + b0 + lane];
                my_src = (int)(q & 0xffffu);
                my_ew = bf2f((unsigned short)(q >> 16)) * dinv[my_src];
            }
            int jp = 0;
            for (; jp + 3 < n; jp += 4) {    // uniform: 2 pairs
                int iA = jp + half, iB = jp + 2 + half;
                int sA = __shfl(my_src, iA, 64);
                float eA = __shfl(my_ew, iA, 64);
                int sB = __shfl(my_src, iB, 64);
                float eB = __shfl(my_ew, iB, 64);
                unsigned hA = *(const unsigned*)(hb + (size_t)sA * D + 2 * cl);
                unsigned hB = *(const unsigned*)(hb + (size_t)sB * D + 2 * cl);
                a0 = fmaf(bf2f((unsigned short)hA), eA, a0);
                a1 = fmaf(bf2f((unsigned short)(hA >> 16)), eA, a1);
                p0 = fmaf(bf2f((unsigned short)hB), eB, p0);
                p1 = fmaf(bf2f((unsigned short)(hB >> 16)), eB, p1);
            }
            for (; jp + 1 < n; jp += 2) {    // uniform: one pair
                int iA = jp + half;
                int sA = __shfl(my_src, iA, 64);
                float eA = __shfl(my_ew, iA, 64);
                unsigned hA = *(const unsigned*)(hb + (size_t)sA * D + 2 * cl);
                a0 = fmaf(bf2f((unsigned short)hA), eA, a0);
                a1 = fmaf(bf2f((unsigned short)(hA >> 16)), eA, a1);
            }
            if (jp < n) {                    // lone edge: uniform shfl, half0 FMA
                int sA = __shfl(my_src, jp, 64);
                float eA = __shfl(my_ew, jp, 64);
                unsigned hA = *(const unsigned*)(hb + (size_t)sA * D + 2 * cl);
                float m = (half == 0) ? eA : 0.0f;
                a0 = fmaf(bf2f((unsigned short)hA), m, a0);
                a1 = fmaf(bf2f((unsigned short)(hA >> 16)), m, a1);
            }
        }
        a0 += p0; a1 += p1;
        a0 += __shfl_xor(a0, 32, 64);        // combine halves
        a1 += __shfl_xor(a1, 32, 64);
        if (half == 0) {
            float v0 = fmaf(di, a0, bias[2 * cl]);
            float v1 = fmaf(di, a1, bias[2 * cl + 1]);
            float2 o;
            o.x = fmaxf(v0, 0.0f);
            o.y = fmaxf(v1, 0.0f);
            *(float2*)(out + (size_t)node * D + 2 * cl) = o;
        }
    }
}

// ---------------- legacy fallback kernels (R14-proven) ----------------

union ShU2 {
    int lh[NBUCK];
    struct { float Ws[D][D]; float Xs[4][D]; } gm;
};
__global__ __launch_bounds__(256) void k_bin_gemm(
        const int* __restrict__ src, const int* __restrict__ dst,
        const float* __restrict__ ew,
        int* __restrict__ gcur, unsigned long long* __restrict__ binned,
        const float* __restrict__ x, const float* __restrict__ W,
        unsigned short* __restrict__ hb) {
    __shared__ ShU2 sh;
    int t = threadIdx.x;
    if (blockIdx.x < BINBLK) {
        int* lh = sh.lh;
        for (int i = t; i < NBUCK; i += 256) lh[i] = 0;
        __syncthreads();
        int base = blockIdx.x * EPB;
#pragma unroll
        for (int i = 0; i < ECHUNK; ++i) {
            int k = i * 256 + t;
            if (k < EPB) atomicAdd(&lh[dst[base + k] >> 6], 1);
        }
        __syncthreads();
        for (int i = t; i < NBUCK; i += 256) {
            int c = lh[i];
            lh[i] = (c > 0) ? atomicAdd(&gcur[i], c) : 0;
        }
        __syncthreads();
#pragma unroll
        for (int i = 0; i < ECHUNK; ++i) {
            int k = i * 256 + t;
            if (k < EPB) {
                int e = base + k;
                int d = dst[e];
                int bkt = d >> 6;
                int pos = atomicAdd(&lh[bkt], 1);
                if (pos < CAP)
                    binned[(size_t)bkt * CAP + pos] =
                        ((unsigned long long)__float_as_uint(ew[e]) << 32)
                      | ((unsigned)src[e] << 16) | (unsigned)d;
            }
        }
    } else {
        float (*Ws)[D] = sh.gm.Ws;
        float (*Xs)[D] = sh.gm.Xs;
        for (int k = t; k < D * D; k += 256) Ws[k / D][k % D] = W[k];
        int base = (blockIdx.x - BINBLK) * 16;
        int r = t >> 6, c = t & 63;
        for (int g = 0; g < 4; ++g) {
            int row = base + g * 4 + r;
            __syncthreads();
            Xs[r][c] = (row < N_NODES) ? x[(size_t)row * D + c] : 0.0f;
            __syncthreads();
            float acc = 0.0f;
#pragma unroll
            for (int k = 0; k < D; ++k) acc = fmaf(Xs[r][k], Ws[k][c], acc);
            if (row < N_NODES) hb[(size_t)row * D + c] = f2bf(acc);
        }
    }
}

__global__ void k_sortbucket(const unsigned long long* __restrict__ binned,
                             const int* __restrict__ gcur,
                             unsigned* __restrict__ csr,
                             unsigned* __restrict__ rc,
                             float* __restrict__ dinv) {
    __shared__ unsigned long long stage[CAP];
    __shared__ unsigned long long cw[64];
    __shared__ int off2[64];
    int t = threadIdx.x;
    if (t < 64) cw[t] = 0ULL;
    __syncthreads();
    int b = blockIdx.x;
    size_t beg = (size_t)b * CAP;
    int len = min(gcur[b], CAP);
    for (int k = t; k < len; k += 256) {
        unsigned long long p = binned[beg + k];
        stage[k] = p;
        int dl = (int)(p & 63);
        float w = __uint_as_float((unsigned)(p >> 32));
        atomicAdd(&cw[dl], (1ULL << 40) | (unsigned long long)__float2uint_rn(w * FIXSCALE));
    }
    __syncthreads();
    if (t < 64) {
        int c = (int)(cw[t] >> 40);
        float wfix = (float)(cw[t] & ((1ULL << 40) - 1ULL));
        int inc = wave_incl_scan(c, t);
        int excl = inc - c;
        off2[t] = excl;
        int node = b * 64 + t;
        if (node < N_NODES) {
            rc[node] = ((unsigned)c << 12) | (unsigned)excl;
            dinv[node] = rsqrtf(1.0f + wfix * (1.0f / FIXSCALE));
        }
    }
    __syncthreads();
    for (int k = t; k < len; k += 256) {
        unsigned long long p = stage[k];
        int dl = (int)(p & 63);
        int r = atomicAdd(&off2[dl], 1);
        unsigned short ewb = f2bf(__uint_as_float((unsigned)(p >> 32)));
        csr[beg + r] = ((unsigned)ewb << 16) | (unsigned)((p >> 16) & 0xffffu);
    }
}

__global__ void k_aggregate(const unsigned short* __restrict__ hb,
                            const float* __restrict__ dinv,
                            const unsigned* __restrict__ rc,
                            const unsigned* __restrict__ csr,
                            const float* __restrict__ bias,
                            float* __restrict__ out) {
    int node = blockIdx.x * 4 + (threadIdx.x >> 6);
    int lane = threadIdx.x & 63;
    if (node >= N_NODES) return;
    int half = lane >> 5;
    int cl = lane & 31;
    float di = dinv[node];
    unsigned r = rc[node];
    int cnt = (int)(r >> 12);
    size_t beg = (size_t)(node >> 6) * CAP + (r & 0xFFFu);
    float a0 = 0.0f, a1 = 0.0f, p0 = 0.0f, p1 = 0.0f;
    {
        unsigned hd = *(const unsigned*)(hb + (size_t)node * D + 2 * cl);
        float m = (half == 0) ? di : 0.0f;
        a0 = m * bf2f((unsigned short)hd);
        a1 = m * bf2f((unsigned short)(hd >> 16));
    }
    for (int b0 = 0; b0 < cnt; b0 += 64) {
        int n = min(64, cnt - b0);
        int my_src = 0;
        float my_ew = 0.0f;
        if (lane < n) {
            unsigned q = csr[beg + b0 + lane];
            my_src = (int)(q & 0xffffu);
            my_ew = bf2f((unsigned short)(q >> 16)) * dinv[my_src];
        }
        int jp = 0;
        for (; jp + 3 < n; jp += 4) {
            int iA = jp + half, iB = jp + 2 + half;
            int sA = __shfl(my_src, iA, 64);
            float eA = __shfl(my_ew, iA, 64);
            int sB = __shfl(my_src, iB, 64);
            float eB = __shfl(my_ew, iB, 64);
            unsigned hA = *(const unsigned*)(hb + (size_t)sA * D + 2 * cl);
            unsigned hB = *(const unsigned*)(hb + (size_t)sB * D + 2 * cl);
            a0 = fmaf(bf2f((unsigned short)hA), eA, a0);
            a1 = fmaf(bf2f((unsigned short)(hA >> 16)), eA, a1);
            p0 = fmaf(bf2f((unsigned short)hB), eB, p0);
            p1 = fmaf(bf2f((unsigned short)(hB >> 16)), eB, p1);
        }
        for (; jp + 1 < n; jp += 2) {
            int iA = jp + half;
            int sA = __shfl(my_src, iA, 64);
            float eA = __shfl(my_ew, iA, 64);
            unsigned hA = *(const unsigned*)(hb + (size_t)sA * D + 2 * cl);
            a0 = fmaf(bf2f((unsigned short)hA), eA, a0);
            a1 = fmaf(bf2f((unsigned short)(hA >> 16)), eA, a1);
        }
        if (jp < n) {
            int sA = __shfl(my_src, jp, 64);
            float eA = __shfl(my_ew, jp, 64);
            unsigned hA = *(const unsigned*)(hb + (size_t)sA * D + 2 * cl);
            float m = (half == 0) ? eA : 0.0f;
            a0 = fmaf(bf2f((unsigned short)hA), m, a0);
            a1 = fmaf(bf2f((unsigned short)(hA >> 16)), m, a1);
        }
    }
    a0 += p0; a1 += p1;
    a0 += __shfl_xor(a0, 32, 64);
    a1 += __shfl_xor(a1, 32, 64);
    if (half == 0) {
        float v0 = fmaf(di, a0, bias[2 * cl]);
        float v1 = fmaf(di, a1, bias[2 * cl + 1]);
        float2 o;
        o.x = fmaxf(v0, 0.0f);
        o.y = fmaxf(v1, 0.0f);
        *(float2*)(out + (size_t)node * D + 2 * cl) = o;
    }
}

// ---------------- launch ----------------

extern "C" void kernel_launch(void* const* d_in, const int* in_sizes, int n_in,
                              void* d_out, int out_size, void* d_ws, size_t ws_size,
                              hipStream_t stream) {
    const float* x  = (const float*)d_in[0];
    const int*   ei = (const int*)d_in[1];    // [2, E] row-major, int32
    const float* ew = (const float*)d_in[2];
    const float* W  = (const float*)d_in[3];
    const float* b  = (const float*)d_in[4];
    float* out = (float*)d_out;

    const int* src = ei;
    const int* dst = ei + N_EDGES;

    // workspace layout (8B-aligned first)
    unsigned long long* binned = (unsigned long long*)d_ws;          // NBUCK*CAP u64 (9.6MB)
    unsigned* csr      = (unsigned*)(binned + (size_t)NBUCK * CAP);  // NBUCK*CAP u32 (4.8MB)
    int*   gcur        = (int*)(csr + (size_t)NBUCK * CAP);          // 1024
    unsigned* rc       = (unsigned*)(gcur + 1024);                   // 50048
    float* dinv        = (float*)(rc + 50048);                       // 50048
    unsigned short* hb = (unsigned short*)(dinv + 50048);            // N*D bf16 (6.4MB)

    // mutable copies for the args array
    const int* a_src = src; const int* a_dst = dst; const float* a_ew = ew;
    int* a_gcur = gcur; unsigned long long* a_binned = binned;
    const float* a_x = x; const float* a_W = W; unsigned short* a_hb = hb;
    unsigned* a_csr = csr; unsigned* a_rc = rc; float* a_dinv = dinv;
    const float* a_b = b; float* a_out = out;
    void* args[] = {&a_src, &a_dst, &a_ew, &a_gcur, &a_binned, &a_x, &a_W,
                    &a_hb, &a_csr, &a_rc, &a_dinv, &a_b, &a_out};

    hipError_t err = hipLaunchCooperativeKernel((const void*)k_fused,
                                                dim3(GRID), dim3(256),
                                                args, 0, stream);
    if (err != hipSuccess) {
        // fallback: proven R14 4-step pipeline
        (void)hipMemsetAsync(gcur, 0, NBUCK * sizeof(int), stream);
        k_bin_gemm<<<BINBLK + GEMMBLK, dim3(256), 0, stream>>>(src, dst, ew, gcur,
                                                               binned, x, W, hb);
        k_sortbucket<<<NBUCK, dim3(256), 0, stream>>>(binned, gcur, csr, rc, dinv);
        k_aggregate<<<AGGBLK, dim3(256), 0, stream>>>(hb, dinv, rc, csr, b, out);
    }
}

// Round 16
// 83.066 us; speedup vs baseline: 8.6930x; 8.6930x over previous
//
#include <hip/hip_runtime.h>

#define N_NODES 50000
#define N_EDGES 800000
#define D 64
#define NBUCK 782            // ceil(50000/64) buckets of 64 dst nodes
#define BINBLK 512           // binning blocks (2 per CU)
#define EPB 1563             // edges per bin block (512*1563 = 800256 >= 800000)
#define ECHUNK 7             // ceil(1563/256)
#define GEMMBLK ((N_NODES + 15) / 16)   // 3125 gemm blocks, 16 rows each
#define CAP 1536             // fixed bucket capacity (mean 1024 + 16 sigma)
#define FIXSCALE 4194304.0f  // 2^22 fixed-point for weighted degree

// ---------------- helpers ----------------

__device__ inline unsigned short f2bf(float f) {
    unsigned u = __float_as_uint(f);
    unsigned r = (u + 0x7FFFu + ((u >> 16) & 1u)) >> 16;   // RNE
    return (unsigned short)r;
}
__device__ inline float bf2f(unsigned short h) {
    return __uint_as_float(((unsigned)h) << 16);
}
__device__ inline int wave_incl_scan(int v, int lane) {
#pragma unroll
    for (int off = 1; off < 64; off <<= 1) {
        int n = __shfl_up(v, off, 64);
        if (lane >= off) v += n;
    }
    return v;
}

// ---------------- kernels ----------------

__global__ void k_zero(int* __restrict__ gcur) {
    int i = blockIdx.x * blockDim.x + threadIdx.x;
    if (i < NBUCK) gcur[i] = 0;
}

// Fused: blocks [0,BINBLK) bin edges into fixed-capacity bucket regions
// (register-stage edges on pass 1, count in LDS, reserve via global atomic,
// scatter from registers); blocks [BINBLK,..) compute hb = bf16(x @ W).
union ShU {
    int lh[NBUCK];                                   // bin: 3.1 KB
    struct { float Ws[D][D]; float Xs[4][D]; } gm;   // 17.4 KB
};
__global__ __launch_bounds__(256) void k_bin_gemm(
        const int* __restrict__ src, const int* __restrict__ dst,
        const float* __restrict__ ew,
        int* __restrict__ gcur, unsigned long long* __restrict__ binned,
        const float* __restrict__ x, const float* __restrict__ W,
        unsigned short* __restrict__ hb) {
    __shared__ ShU sh;
    int t = threadIdx.x;
    if (blockIdx.x < BINBLK) {
        int rd[ECHUNK]; int rs[ECHUNK]; float rw[ECHUNK];   // 21 VGPRs staging
        int* lh = sh.lh;
        for (int i = t; i < NBUCK; i += 256) lh[i] = 0;
        __syncthreads();
        int base = blockIdx.x * EPB;
#pragma unroll
        for (int i = 0; i < ECHUNK; ++i) {          // pass 1: load + count
            int k = i * 256 + t;
            rd[i] = -1;
            if (k < EPB) {
                int e = base + k;
                if (e < N_EDGES) {
                    rd[i] = dst[e];
                    rs[i] = src[e];
                    rw[i] = ew[e];
                    atomicAdd(&lh[rd[i] >> 6], 1);
                }
            }
        }
        __syncthreads();
        for (int i = t; i < NBUCK; i += 256) {
            int c = lh[i];
            lh[i] = (c > 0) ? atomicAdd(&gcur[i], c) : 0;   // block's run base
        }
        __syncthreads();
#pragma unroll
        for (int i = 0; i < ECHUNK; ++i) {          // pass 2: scatter from regs
            if (rd[i] >= 0) {
                int bkt = rd[i] >> 6;
                int pos = atomicAdd(&lh[bkt], 1);
                if (pos < CAP)
                    binned[(size_t)bkt * CAP + pos] =
                        ((unsigned long long)__float_as_uint(rw[i]) << 32)
                      | ((unsigned)rs[i] << 16) | (unsigned)rd[i];
            }
        }
    } else {
        float (*Ws)[D] = sh.gm.Ws;
        float (*Xs)[D] = sh.gm.Xs;
        for (int k = t; k < D * D; k += 256) Ws[k / D][k % D] = W[k];
        int base = (blockIdx.x - BINBLK) * 16;
        int r = t >> 6, c = t & 63;
        for (int g = 0; g < 4; ++g) {
            int row = base + g * 4 + r;
            __syncthreads();   // covers Ws staging (g=0) and Xs reuse (g>0)
            Xs[r][c] = (row < N_NODES) ? x[(size_t)row * D + c] : 0.0f;
            __syncthreads();
            float acc = 0.0f;
#pragma unroll
            for (int k = 0; k < D; ++k) acc = fmaf(Xs[r][k], Ws[k][c], acc);
            if (row < N_NODES) hb[(size_t)row * D + c] = f2bf(acc);
        }
    }
}

// one block per bucket: counting-sort to per-node CSR (u32 bf16ew|src) within
// the padded region; fused weighted degree -> dinv; rc = (cnt<<12)|excl
__global__ void k_sortbucket(const unsigned long long* __restrict__ binned,
                             const int* __restrict__ gcur,
                             unsigned* __restrict__ csr,
                             unsigned* __restrict__ rc,
                             float* __restrict__ dinv) {
    __shared__ unsigned long long stage[CAP];   // 12 KB
    __shared__ unsigned long long cw[64];       // (cnt<<40) | fix22 wsum
    __shared__ int off2[64];
    int t = threadIdx.x;
    if (t < 64) cw[t] = 0ULL;
    __syncthreads();
    int b = blockIdx.x;
    size_t beg = (size_t)b * CAP;
    int len = min(gcur[b], CAP);
    for (int k = t; k < len; k += 256) {
        unsigned long long p = binned[beg + k];
        stage[k] = p;
        int dl = (int)(p & 63);
        float w = __uint_as_float((unsigned)(p >> 32));
        atomicAdd(&cw[dl], (1ULL << 40) | (unsigned long long)__float2uint_rn(w * FIXSCALE));
    }
    __syncthreads();
    if (t < 64) {
        int c = (int)(cw[t] >> 40);
        float wfix = (float)(cw[t] & ((1ULL << 40) - 1ULL));
        int inc = wave_incl_scan(c, t);
        int excl = inc - c;
        off2[t] = excl;
        int node = b * 64 + t;
        if (node < N_NODES) {
            rc[node] = ((unsigned)c << 12) | (unsigned)excl;
            dinv[node] = rsqrtf(1.0f + wfix * (1.0f / FIXSCALE));
        }
    }
    __syncthreads();
    for (int k = t; k < len; k += 256) {
        unsigned long long p = stage[k];
        int dl = (int)(p & 63);
        int r = atomicAdd(&off2[dl], 1);
        unsigned short ewb = f2bf(__uint_as_float((unsigned)(p >> 32)));
        csr[beg + r] = ((unsigned)ewb << 16) | (unsigned)((p >> 16) & 0xffffu);
    }
}

// one wave per node, two 32-lane halves processing alternate edges of each
// pair — control flow is WAVE-UNIFORM (shfl always executed with all lanes
// active; per-lane shfl index jp+half is a legal bpermute).
__global__ void k_aggregate(const unsigned short* __restrict__ hb,
                            const float* __restrict__ dinv,
                            const unsigned* __restrict__ rc,
                            const unsigned* __restrict__ csr,
                            const float* __restrict__ bias,
                            float* __restrict__ out) {
    int node = blockIdx.x * 4 + (threadIdx.x >> 6);
    int lane = threadIdx.x & 63;
    if (node >= N_NODES) return;
    int half = lane >> 5;
    int cl = lane & 31;          // column pair: cols 2cl, 2cl+1
    float di = dinv[node];
    unsigned r = rc[node];
    int cnt = (int)(r >> 12);
    size_t beg = (size_t)(node >> 6) * CAP + (r & 0xFFFu);
    float a0 = 0.0f, a1 = 0.0f, p0 = 0.0f, p1 = 0.0f;
    {   // self-loop term, counted once (half 0 lanes)
        unsigned hd = *(const unsigned*)(hb + (size_t)node * D + 2 * cl);
        float m = (half == 0) ? di : 0.0f;
        a0 = m * bf2f((unsigned short)hd);
        a1 = m * bf2f((unsigned short)(hd >> 16));
    }
    for (int b0 = 0; b0 < cnt; b0 += 64) {
        int n = min(64, cnt - b0);
        int my_src = 0;
        float my_ew = 0.0f;
        if (lane < n) {
            unsigned q = csr[beg + b0 + lane];
            my_src = (int)(q & 0xffffu);
            my_ew = bf2f((unsigned short)(q >> 16)) * dinv[my_src];  // L2-resident
        }
        int jp = 0;
        for (; jp + 3 < n; jp += 4) {        // uniform: pairs (jp, jp+1), (jp+2, jp+3)
            int iA = jp + half, iB = jp + 2 + half;
            int sA = __shfl(my_src, iA, 64);
            float eA = __shfl(my_ew, iA, 64);
            int sB = __shfl(my_src, iB, 64);
            float eB = __shfl(my_ew, iB, 64);
            unsigned hA = *(const unsigned*)(hb + (size_t)sA * D + 2 * cl);
            unsigned hB = *(const unsigned*)(hb + (size_t)sB * D + 2 * cl);
            a0 = fmaf(bf2f((unsigned short)hA), eA, a0);
            a1 = fmaf(bf2f((unsigned short)(hA >> 16)), eA, a1);
            p0 = fmaf(bf2f((unsigned short)hB), eB, p0);
            p1 = fmaf(bf2f((unsigned short)(hB >> 16)), eB, p1);
        }
        for (; jp + 1 < n; jp += 2) {        // uniform: one pair
            int iA = jp + half;
            int sA = __shfl(my_src, iA, 64);
            float eA = __shfl(my_ew, iA, 64);
            unsigned hA = *(const unsigned*)(hb + (size_t)sA * D + 2 * cl);
            a0 = fmaf(bf2f((unsigned short)hA), eA, a0);
            a1 = fmaf(bf2f((unsigned short)(hA >> 16)), eA, a1);
        }
        if (jp < n) {                        // lone last edge: uniform shfl, half0 FMA
            int sA = __shfl(my_src, jp, 64);
            float eA = __shfl(my_ew, jp, 64);
            unsigned hA = *(const unsigned*)(hb + (size_t)sA * D + 2 * cl);
            float m = (half == 0) ? eA : 0.0f;
            a0 = fmaf(bf2f((unsigned short)hA), m, a0);
            a1 = fmaf(bf2f((unsigned short)(hA >> 16)), m, a1);
        }
    }
    a0 += p0; a1 += p1;
    a0 += __shfl_xor(a0, 32, 64);            // combine halves
    a1 += __shfl_xor(a1, 32, 64);
    if (half == 0) {
        float v0 = fmaf(di, a0, bias[2 * cl]);
        float v1 = fmaf(di, a1, bias[2 * cl + 1]);
        float2 o;
        o.x = fmaxf(v0, 0.0f);
        o.y = fmaxf(v1, 0.0f);
        *(float2*)(out + (size_t)node * D + 2 * cl) = o;
    }
}

// ---------------- launch ----------------

extern "C" void kernel_launch(void* const* d_in, const int* in_sizes, int n_in,
                              void* d_out, int out_size, void* d_ws, size_t ws_size,
                              hipStream_t stream) {
    const float* x  = (const float*)d_in[0];
    const int*   ei = (const int*)d_in[1];    // [2, E] row-major, int32
    const float* ew = (const float*)d_in[2];
    const float* W  = (const float*)d_in[3];
    const float* b  = (const float*)d_in[4];
    float* out = (float*)d_out;

    const int* src = ei;
    const int* dst = ei + N_EDGES;

    // workspace layout (8B-aligned first)
    unsigned long long* binned = (unsigned long long*)d_ws;          // NBUCK*CAP u64 (9.6MB)
    unsigned* csr      = (unsigned*)(binned + (size_t)NBUCK * CAP);  // NBUCK*CAP u32 (4.8MB)
    int*   gcur        = (int*)(csr + (size_t)NBUCK * CAP);          // 1024
    unsigned* rc       = (unsigned*)(gcur + 1024);                   // 50048
    float* dinv        = (float*)(rc + 50048);                       // 50048
    unsigned short* hb = (unsigned short*)(dinv + 50048);            // N*D bf16 (6.4MB)

    dim3 blk(256);
    k_zero<<<4, blk, 0, stream>>>(gcur);
    k_bin_gemm<<<BINBLK + GEMMBLK, blk, 0, stream>>>(src, dst, ew, gcur, binned,
                                                     x, W, hb);
    k_sortbucket<<<NBUCK, blk, 0, stream>>>(binned, gcur, csr, rc, dinv);
    k_aggregate<<<(N_NODES + 3) / 4, blk, 0, stream>>>(hb, dinv, rc, csr, b, out);
}

// Round 17
// 76.006 us; speedup vs baseline: 9.5005x; 1.0929x over previous
//
#include <hip/hip_runtime.h>

#define N_NODES 50000
#define N_EDGES 800000
#define D 64
#define NBUCK 782            // ceil(50000/64) buckets of 64 dst nodes
#define BINBLK 256           // binning blocks (long runs: ~4 edges/bucket/block)
#define EPB 3125             // edges per bin block (256*3125 = 800000)
#define ECHUNK 13            // ceil(3125/256)
#define GEMMBLK ((N_NODES + 15) / 16)   // 3125 gemm blocks, 16 rows each
#define CAP 1536             // fixed bucket capacity (mean 1024 + 16 sigma)
#define FIXSCALE 4194304.0f  // 2^22 fixed-point for weighted degree

// ---------------- helpers ----------------

__device__ inline unsigned short f2bf(float f) {
    unsigned u = __float_as_uint(f);
    unsigned r = (u + 0x7FFFu + ((u >> 16) & 1u)) >> 16;   // RNE
    return (unsigned short)r;
}
__device__ inline float bf2f(unsigned short h) {
    return __uint_as_float(((unsigned)h) << 16);
}
__device__ inline int wave_incl_scan(int v, int lane) {
#pragma unroll
    for (int off = 1; off < 64; off <<= 1) {
        int n = __shfl_up(v, off, 64);
        if (lane >= off) v += n;
    }
    return v;
}

// ---------------- kernels ----------------

__global__ void k_zero(int* __restrict__ gcur) {
    int i = blockIdx.x * blockDim.x + threadIdx.x;
    if (i < NBUCK) gcur[i] = 0;
}

// Fused: blocks [0,BINBLK) bin edges into fixed-capacity bucket regions
// (register-stage edges on pass 1, count in LDS, reserve via global atomic,
// scatter from registers — no second edge read);
// blocks [BINBLK,..) compute hb = bf16(x @ W).
union ShU {
    int lh[NBUCK];                                   // bin: 3.1 KB
    struct { float Ws[D][D]; float Xs[4][D]; } gm;   // 17.4 KB
};
__global__ __launch_bounds__(256) void k_bin_gemm(
        const int* __restrict__ src, const int* __restrict__ dst,
        const float* __restrict__ ew,
        int* __restrict__ gcur, unsigned long long* __restrict__ binned,
        const float* __restrict__ x, const float* __restrict__ W,
        unsigned short* __restrict__ hb) {
    __shared__ ShU sh;
    int t = threadIdx.x;
    if (blockIdx.x < BINBLK) {
        int rd[ECHUNK]; int rs[ECHUNK]; float rw[ECHUNK];   // 39 VGPRs staging
        int* lh = sh.lh;
        for (int i = t; i < NBUCK; i += 256) lh[i] = 0;
        __syncthreads();
        int base = blockIdx.x * EPB;
#pragma unroll
        for (int i = 0; i < ECHUNK; ++i) {          // pass 1: load + count
            int k = i * 256 + t;
            rd[i] = -1;
            if (k < EPB) {
                int e = base + k;
                rd[i] = dst[e];
                rs[i] = src[e];
                rw[i] = ew[e];
                atomicAdd(&lh[rd[i] >> 6], 1);
            }
        }
        __syncthreads();
        for (int i = t; i < NBUCK; i += 256) {
            int c = lh[i];
            lh[i] = (c > 0) ? atomicAdd(&gcur[i], c) : 0;   // block's run base
        }
        __syncthreads();
#pragma unroll
        for (int i = 0; i < ECHUNK; ++i) {          // pass 2: scatter from regs
            if (rd[i] >= 0) {
                int bkt = rd[i] >> 6;
                int pos = atomicAdd(&lh[bkt], 1);
                if (pos < CAP)
                    binned[(size_t)bkt * CAP + pos] =
                        ((unsigned long long)__float_as_uint(rw[i]) << 32)
                      | ((unsigned)rs[i] << 16) | (unsigned)rd[i];
            }
        }
    } else {
        float (*Ws)[D] = sh.gm.Ws;
        float (*Xs)[D] = sh.gm.Xs;
        for (int k = t; k < D * D; k += 256) Ws[k / D][k % D] = W[k];
        int base = (blockIdx.x - BINBLK) * 16;
        int r = t >> 6, c = t & 63;
        for (int g = 0; g < 4; ++g) {
            int row = base + g * 4 + r;
            __syncthreads();   // covers Ws staging (g=0) and Xs reuse (g>0)
            Xs[r][c] = (row < N_NODES) ? x[(size_t)row * D + c] : 0.0f;
            __syncthreads();
            float acc = 0.0f;
#pragma unroll
            for (int k = 0; k < D; ++k) acc = fmaf(Xs[r][k], Ws[k][c], acc);
            if (row < N_NODES) hb[(size_t)row * D + c] = f2bf(acc);
        }
    }
}

// one block per bucket: counting-sort to per-node CSR (u32 bf16ew|src) within
// the padded region; fused weighted degree -> dinv; rc = (cnt<<12)|excl
__global__ void k_sortbucket(const unsigned long long* __restrict__ binned,
                             const int* __restrict__ gcur,
                             unsigned* __restrict__ csr,
                             unsigned* __restrict__ rc,
                             float* __restrict__ dinv) {
    __shared__ unsigned long long stage[CAP];   // 12 KB
    __shared__ unsigned long long cw[64];       // (cnt<<40) | fix22 wsum
    __shared__ int off2[64];
    int t = threadIdx.x;
    if (t < 64) cw[t] = 0ULL;
    __syncthreads();
    int b = blockIdx.x;
    size_t beg = (size_t)b * CAP;
    int len = min(gcur[b], CAP);
    for (int k = t; k < len; k += 256) {
        unsigned long long p = binned[beg + k];
        stage[k] = p;
        int dl = (int)(p & 63);
        float w = __uint_as_float((unsigned)(p >> 32));
        atomicAdd(&cw[dl], (1ULL << 40) | (unsigned long long)__float2uint_rn(w * FIXSCALE));
    }
    __syncthreads();
    if (t < 64) {
        int c = (int)(cw[t] >> 40);
        float wfix = (float)(cw[t] & ((1ULL << 40) - 1ULL));
        int inc = wave_incl_scan(c, t);
        int excl = inc - c;
        off2[t] = excl;
        int node = b * 64 + t;
        if (node < N_NODES) {
            rc[node] = ((unsigned)c << 12) | (unsigned)excl;
            dinv[node] = rsqrtf(1.0f + wfix * (1.0f / FIXSCALE));
        }
    }
    __syncthreads();
    for (int k = t; k < len; k += 256) {
        unsigned long long p = stage[k];
        int dl = (int)(p & 63);
        int r = atomicAdd(&off2[dl], 1);
        unsigned short ewb = f2bf(__uint_as_float((unsigned)(p >> 32)));
        csr[beg + r] = ((unsigned)ewb << 16) | (unsigned)((p >> 16) & 0xffffu);
    }
}

// one wave per node, two 32-lane halves processing alternate edges of each
// pair — control flow is WAVE-UNIFORM (shfl always executed with all lanes
// active; per-lane shfl index jp+half is a legal bpermute).
__global__ void k_aggregate(const unsigned short* __restrict__ hb,
                            const float* __restrict__ dinv,
                            const unsigned* __restrict__ rc,
                            const unsigned* __restrict__ csr,
                            const float* __restrict__ bias,
                            float* __restrict__ out) {
    int node = blockIdx.x * 4 + (threadIdx.x >> 6);
    int lane = threadIdx.x & 63;
    if (node >= N_NODES) return;
    int half = lane >> 5;
    int cl = lane & 31;          // column pair: cols 2cl, 2cl+1
    float di = dinv[node];
    unsigned r = rc[node];
    int cnt = (int)(r >> 12);
    size_t beg = (size_t)(node >> 6) * CAP + (r & 0xFFFu);
    float a0 = 0.0f, a1 = 0.0f, p0 = 0.0f, p1 = 0.0f;
    {   // self-loop term, counted once (half 0 lanes)
        unsigned hd = *(const unsigned*)(hb + (size_t)node * D + 2 * cl);
        float m = (half == 0) ? di : 0.0f;
        a0 = m * bf2f((unsigned short)hd);
        a1 = m * bf2f((unsigned short)(hd >> 16));
    }
    for (int b0 = 0; b0 < cnt; b0 += 64) {
        int n = min(64, cnt - b0);
        int my_src = 0;
        float my_ew = 0.0f;
        if (lane < n) {
            unsigned q = csr[beg + b0 + lane];
            my_src = (int)(q & 0xffffu);
            my_ew = bf2f((unsigned short)(q >> 16)) * dinv[my_src];  // L2-resident
        }
        int jp = 0;
        for (; jp + 3 < n; jp += 4) {        // uniform: pairs (jp, jp+1), (jp+2, jp+3)
            int iA = jp + half, iB = jp + 2 + half;
            int sA = __shfl(my_src, iA, 64);
            float eA = __shfl(my_ew, iA, 64);
            int sB = __shfl(my_src, iB, 64);
            float eB = __shfl(my_ew, iB, 64);
            unsigned hA = *(const unsigned*)(hb + (size_t)sA * D + 2 * cl);
            unsigned hB = *(const unsigned*)(hb + (size_t)sB * D + 2 * cl);
            a0 = fmaf(bf2f((unsigned short)hA), eA, a0);
            a1 = fmaf(bf2f((unsigned short)(hA >> 16)), eA, a1);
            p0 = fmaf(bf2f((unsigned short)hB), eB, p0);
            p1 = fmaf(bf2f((unsigned short)(hB >> 16)), eB, p1);
        }
        for (; jp + 1 < n; jp += 2) {        // uniform: one pair
            int iA = jp + half;
            int sA = __shfl(my_src, iA, 64);
            float eA = __shfl(my_ew, iA, 64);
            unsigned hA = *(const unsigned*)(hb + (size_t)sA * D + 2 * cl);
            a0 = fmaf(bf2f((unsigned short)hA), eA, a0);
            a1 = fmaf(bf2f((unsigned short)(hA >> 16)), eA, a1);
        }
        if (jp < n) {                        // lone last edge: uniform shfl, half0 FMA
            int sA = __shfl(my_src, jp, 64);
            float eA = __shfl(my_ew, jp, 64);
            unsigned hA = *(const unsigned*)(hb + (size_t)sA * D + 2 * cl);
            float m = (half == 0) ? eA : 0.0f;
            a0 = fmaf(bf2f((unsigned short)hA), m, a0);
            a1 = fmaf(bf2f((unsigned short)(hA >> 16)), m, a1);
        }
    }
    a0 += p0; a1 += p1;
    a0 += __shfl_xor(a0, 32, 64);            // combine halves
    a1 += __shfl_xor(a1, 32, 64);
    if (half == 0) {
        float v0 = fmaf(di, a0, bias[2 * cl]);
        float v1 = fmaf(di, a1, bias[2 * cl + 1]);
        float2 o;
        o.x = fmaxf(v0, 0.0f);
        o.y = fmaxf(v1, 0.0f);
        *(float2*)(out + (size_t)node * D + 2 * cl) = o;
    }
}

// ---------------- launch ----------------

extern "C" void kernel_launch(void* const* d_in, const int* in_sizes, int n_in,
                              void* d_out, int out_size, void* d_ws, size_t ws_size,
                              hipStream_t stream) {
    const float* x  = (const float*)d_in[0];
    const int*   ei = (const int*)d_in[1];    // [2, E] row-major, int32
    const float* ew = (const float*)d_in[2];
    const float* W  = (const float*)d_in[3];
    const float* b  = (const float*)d_in[4];
    float* out = (float*)d_out;

    const int* src = ei;
    const int* dst = ei + N_EDGES;

    // workspace layout (8B-aligned first)
    unsigned long long* binned = (unsigned long long*)d_ws;          // NBUCK*CAP u64 (9.6MB)
    unsigned* csr      = (unsigned*)(binned + (size_t)NBUCK * CAP);  // NBUCK*CAP u32 (4.8MB)
    int*   gcur        = (int*)(csr + (size_t)NBUCK * CAP);          // 1024
    unsigned* rc       = (unsigned*)(gcur + 1024);                   // 50048
    float* dinv        = (float*)(rc + 50048);                       // 50048
    unsigned short* hb = (unsigned short*)(dinv + 50048);            // N*D bf16 (6.4MB)

    dim3 blk(256);
    k_zero<<<4, blk, 0, stream>>>(gcur);
    k_bin_gemm<<<BINBLK + GEMMBLK, blk, 0, stream>>>(src, dst, ew, gcur, binned,
                                                     x, W, hb);
    k_sortbucket<<<NBUCK, blk, 0, stream>>>(binned, gcur, csr, rc, dinv);
    k_aggregate<<<(N_NODES + 3) / 4, blk, 0, stream>>>(hb, dinv, rc, csr, b, out);
}